// Round 3
// baseline (1224.493 us; speedup 1.0000x reference)
//
#include <hip/hip_runtime.h>
#include <math.h>

#define LATD 32
#define AV 40
#define NBOND 4
#define BATCH 256
#define LSRC 400
#define NT 38400
#define NA 38400
#define NBD 76800

typedef unsigned short ushort_t;
typedef short short8 __attribute__((ext_vector_type(8)));
typedef float f32x4 __attribute__((ext_vector_type(4)));
typedef unsigned short ushort4v __attribute__((ext_vector_type(4)));
typedef unsigned short ushort8v __attribute__((ext_vector_type(8)));

__device__ __forceinline__ ushort_t f2bf(float f) {
    union { float f; unsigned u; } v; v.f = f;
    unsigned r = v.u + 0x7fffu + ((v.u >> 16) & 1u);   // RTNE
    return (ushort_t)(r >> 16);
}
__device__ __forceinline__ float bf2f(ushort_t u) {
    union { unsigned u; float f; } v; v.u = ((unsigned)u) << 16;
    return v.f;
}

// ---------------------------------------------------------------------------
// init: zero loss accumulators (8 floats) + histogram counts (3*256 ints)
// ---------------------------------------------------------------------------
__global__ void init_kernel(float* acc, int* cnt) {
    int t = threadIdx.x;
    if (t < 8) acc[t] = 0.0f;
    cnt[t] = 0; cnt[t + 256] = 0; cnt[t + 512] = 0;
}

// ---------------------------------------------------------------------------
// convbf: f32 -> bf16 bulk conversion (weights, done once per launch set)
// n4 = element count / 4
// ---------------------------------------------------------------------------
__global__ __launch_bounds__(256) void convbf_kernel(const float* __restrict__ in,
                                                     ushort_t* __restrict__ out, int n4) {
    int i = blockIdx.x * 256 + threadIdx.x;
    if (i < n4) {
        float4 v = ((const float4*)in)[i];
        ushort4v p;
        p[0] = f2bf(v.x); p[1] = f2bf(v.y); p[2] = f2bf(v.z); p[3] = f2bf(v.w);
        ((ushort4v*)out)[i] = p;
    }
}

// ---------------------------------------------------------------------------
// histogram
// ---------------------------------------------------------------------------
__global__ __launch_bounds__(256) void hist_kernel(const int* __restrict__ idx, int N,
                                                   int* __restrict__ cnt) {
    __shared__ int lc[256];
    int t = threadIdx.x;
    lc[t] = 0;
    __syncthreads();
    for (int i = blockIdx.x * 256 + t; i < N; i += gridDim.x * 256)
        atomicAdd(&lc[idx[i]], 1);
    __syncthreads();
    if (lc[t]) atomicAdd(&cnt[t], lc[t]);
}

// ---------------------------------------------------------------------------
// scan: exclusive prefix over 256 bins, 3 heads
// ---------------------------------------------------------------------------
__global__ __launch_bounds__(256) void scan_kernel(const int* __restrict__ cnt,
                                                   int* __restrict__ cur,
                                                   int* __restrict__ bstart) {
    __shared__ int s[256];
    int t = threadIdx.x;
    for (int h = 0; h < 3; ++h) {
        int v = cnt[h * 256 + t];
        s[t] = v;
        __syncthreads();
        for (int d = 1; d < 256; d <<= 1) {
            int u = (t >= d) ? s[t - d] : 0;
            __syncthreads();
            s[t] += u;
            __syncthreads();
        }
        cur[h * 256 + t] = s[t] - v;
        bstart[h * 256 + t] = s[t] - v;
        __syncthreads();
    }
}

// ---------------------------------------------------------------------------
// scatter: bucket[pos] = row
// ---------------------------------------------------------------------------
__global__ __launch_bounds__(256) void scatter_kernel(const int* __restrict__ idx, int N,
                                                      int* __restrict__ cur,
                                                      int* __restrict__ bucket) {
    for (int i = blockIdx.x * 256 + threadIdx.x; i < N; i += gridDim.x * 256) {
        int b = idx[i];
        int p = atomicAdd(&cur[b], 1);
        bucket[p] = i;
    }
}

// ---------------------------------------------------------------------------
// qproj: Qbf[N,32] = bf16( X[N,DIN] @ Aw^T[DIN,32] + Ab )
// ---------------------------------------------------------------------------
template<int DIN>
__global__ __launch_bounds__(256) void qproj_kernel(
    const float* __restrict__ X,   // [N, DIN]
    const float* __restrict__ Aw,  // [32, DIN]
    const float* __restrict__ Ab,  // [32]
    ushort_t* __restrict__ Qbf)    // [N, 32] bf16
{
    __shared__ ushort_t As[64 * 72];
    __shared__ ushort_t Bs[32 * 72];
    const int tid = threadIdx.x;
    const int wave = tid >> 6, lane = tid & 63;
    const int l15 = lane & 15, quad = lane >> 4;
    const int row0 = blockIdx.x * 64;

    const int ar = tid >> 2;            // 0..63
    const int ak = (tid & 3) * 8;       // 0,8,16,24
    const int br = tid >> 3;            // 0..31
    const int bk = (tid & 7) * 8;       // 0..56

    f32x4 acc0 = {0.f,0.f,0.f,0.f}, acc1 = {0.f,0.f,0.f,0.f};

    for (int k0 = 0; k0 < DIN; k0 += 64) {
        {
            const float* xb = X + (size_t)(row0 + ar) * DIN + k0 + ak;
            float4 v0 = *(const float4*)xb,        v1 = *(const float4*)(xb + 4);
            float4 v2 = *(const float4*)(xb + 32), v3 = *(const float4*)(xb + 36);
            ushort8v p;
            p[0]=f2bf(v0.x); p[1]=f2bf(v0.y); p[2]=f2bf(v0.z); p[3]=f2bf(v0.w);
            p[4]=f2bf(v1.x); p[5]=f2bf(v1.y); p[6]=f2bf(v1.z); p[7]=f2bf(v1.w);
            *(ushort8v*)&As[ar * 72 + ak] = p;
            p[0]=f2bf(v2.x); p[1]=f2bf(v2.y); p[2]=f2bf(v2.z); p[3]=f2bf(v2.w);
            p[4]=f2bf(v3.x); p[5]=f2bf(v3.y); p[6]=f2bf(v3.z); p[7]=f2bf(v3.w);
            *(ushort8v*)&As[ar * 72 + ak + 32] = p;
        }
        {
            const float* wb = Aw + (size_t)br * DIN + k0 + bk;
            float4 w0 = *(const float4*)wb, w1 = *(const float4*)(wb + 4);
            ushort8v p;
            p[0]=f2bf(w0.x); p[1]=f2bf(w0.y); p[2]=f2bf(w0.z); p[3]=f2bf(w0.w);
            p[4]=f2bf(w1.x); p[5]=f2bf(w1.y); p[6]=f2bf(w1.z); p[7]=f2bf(w1.w);
            *(ushort8v*)&Bs[br * 72 + bk] = p;
        }
        __syncthreads();
        short8 a0 = *(const short8*)&As[(wave*16 + l15) * 72 + quad*8];
        short8 a1 = *(const short8*)&As[(wave*16 + l15) * 72 + 32 + quad*8];
        short8 b0 = *(const short8*)&Bs[l15 * 72 + quad*8];
        short8 b1 = *(const short8*)&Bs[l15 * 72 + 32 + quad*8];
        short8 b2 = *(const short8*)&Bs[(16 + l15) * 72 + quad*8];
        short8 b3 = *(const short8*)&Bs[(16 + l15) * 72 + 32 + quad*8];
        acc0 = __builtin_amdgcn_mfma_f32_16x16x32_bf16(a0, b0, acc0, 0, 0, 0);
        acc0 = __builtin_amdgcn_mfma_f32_16x16x32_bf16(a1, b1, acc0, 0, 0, 0);
        acc1 = __builtin_amdgcn_mfma_f32_16x16x32_bf16(a0, b2, acc1, 0, 0, 0);
        acc1 = __builtin_amdgcn_mfma_f32_16x16x32_bf16(a1, b3, acc1, 0, 0, 0);
        __syncthreads();
    }
    const float ab0 = Ab[l15];
    const float ab1 = Ab[16 + l15];
#pragma unroll
    for (int r = 0; r < 4; ++r) {
        int row = row0 + wave*16 + quad*4 + r;
        Qbf[(size_t)row * 32 + l15]      = f2bf(acc0[r] + ab0);
        Qbf[(size_t)row * 32 + 16 + l15] = f2bf(acc1[r] + ab1);
    }
}

// ---------------------------------------------------------------------------
// attn2 (unchanged from round 2)
// ---------------------------------------------------------------------------
template<int TPB, int NBLK>
__global__ __launch_bounds__(256) void attn2_kernel(
    const float* __restrict__ src,      // [256, 400, 32]
    const ushort_t* __restrict__ Qbf,   // [N, 32] bf16
    const int* __restrict__ bucket,
    const int* __restrict__ bstart,     // [256]
    const int* __restrict__ cnt,        // [256]
    ushort_t* __restrict__ cxtb)        // [N, 32] bf16
{
    const int m  = blockIdx.x / NBLK;
    const int t0 = (blockIdx.x % NBLK) * TPB;
    const int cm = cnt[m];
    if (t0 * 32 >= cm) return;

    __shared__ __align__(16) char smem[54272];
    ushort_t* sSrcT  = (ushort_t*)(smem);            // [32][418]  26752 B
    ushort_t* sP     = (ushort_t*)(smem + 26752);    // [32][420]  26880 B
    float*    sStats = (float*)(smem + 53632);       // [4][16][2]   512 B
    int*      sRows  = (int*)(smem + 54144);         // [32]         128 B

    const int tid = threadIdx.x;
    const int wave = tid >> 6, lane = tid & 63;
    const int l15 = lane & 15, quad = lane >> 4;
    const int mt = wave & 1;        // q-row half
    const int nt = wave >> 1;       // chunk parity / output d half
    const bool full = (nt == 0);    // 13th chunk active only for parity 0

    {
        const float4* s4 = (const float4*)(src + (size_t)m * (LSRC * LATD));
        for (int i = tid; i < 3200; i += 256) {
            float4 v = s4[i];
            int l = i >> 3, d4 = (i & 7) * 4;
            sSrcT[(d4 + 0) * 418 + l] = f2bf(v.x);
            sSrcT[(d4 + 1) * 418 + l] = f2bf(v.y);
            sSrcT[(d4 + 2) * 418 + l] = f2bf(v.z);
            sSrcT[(d4 + 3) * 418 + l] = f2bf(v.w);
        }
        for (int i = tid; i < 512; i += 256) {
            int d = i >> 4, l = 400 + (i & 15);
            sSrcT[d * 418 + l] = 0;
        }
        for (int i = tid; i < 512; i += 256) {
            int row = i >> 4, col = 400 + (i & 15);
            sP[row * 420 + col] = 0;
        }
    }
    __syncthreads();

    const int Tm = (cm + 31) >> 5;
    const int rem = Tm - t0;
    const int ntiles = rem < TPB ? rem : TPB;

    for (int tt = 0; tt < ntiles; ++tt) {
        const int t = t0 + tt;
        if (tid < 32) {
            int p = t * 32 + tid;
            sRows[tid] = (p < cm) ? bucket[bstart[m] + p] : -1;
        }
        __syncthreads();

        const int grow = sRows[mt * 16 + l15];
        short8 aq = {0,0,0,0,0,0,0,0};
        if (grow >= 0)
            aq = *(const short8*)(Qbf + (size_t)grow * 32 + quad * 8);

        f32x4 sc[13];
#pragma unroll
        for (int j = 0; j < 13; ++j) {
            int c = nt + 2 * j;                 // c<=25; chunk 25 reads zero pad
            int bbase = quad * 8 * 418 + c * 16 + l15;
            short8 bv;
#pragma unroll
            for (int e = 0; e < 8; ++e) bv[e] = (short)sSrcT[bbase + e * 418];
            f32x4 z = {0.f, 0.f, 0.f, 0.f};
            sc[j] = __builtin_amdgcn_mfma_f32_16x16x32_bf16(aq, bv, z, 0, 0, 0);
        }

        float Mr[4], Sr[4];
#pragma unroll
        for (int r = 0; r < 4; ++r) {
            float mx = sc[0][r];
#pragma unroll
            for (int j = 1; j < 12; ++j) mx = fmaxf(mx, sc[j][r]);
            if (full) mx = fmaxf(mx, sc[12][r]);
            float s = 0.f;
#pragma unroll
            for (int j = 0; j < 12; ++j) s += __expf(sc[j][r] - mx);
            if (full) s += __expf(sc[12][r] - mx);
            Mr[r] = mx; Sr[r] = s;
        }
#pragma unroll
        for (int msk = 1; msk < 16; msk <<= 1) {
#pragma unroll
            for (int r = 0; r < 4; ++r) {
                float mo = __shfl_xor(Mr[r], msk, 64);
                float so = __shfl_xor(Sr[r], msk, 64);
                float mn = fmaxf(Mr[r], mo);
                Sr[r] = Sr[r] * __expf(Mr[r] - mn) + so * __expf(mo - mn);
                Mr[r] = mn;
            }
        }
        if (l15 == 0) {
#pragma unroll
            for (int r = 0; r < 4; ++r) {
                sStats[(wave * 16 + quad * 4 + r) * 2 + 0] = Mr[r];
                sStats[(wave * 16 + quad * 4 + r) * 2 + 1] = Sr[r];
            }
        }
        __syncthreads();
        {
            const int pw = wave ^ 2;   // partner wave, same mt, other parity
#pragma unroll
            for (int r = 0; r < 4; ++r) {
                float mo = sStats[(pw * 16 + quad * 4 + r) * 2 + 0];
                float so = sStats[(pw * 16 + quad * 4 + r) * 2 + 1];
                float mn = fmaxf(Mr[r], mo);
                float L = Sr[r] * __expf(Mr[r] - mn) + so * __expf(mo - mn);
                Mr[r] = mn; Sr[r] = 1.0f / L;
            }
        }
#pragma unroll
        for (int j = 0; j < 12; ++j) {
            int col = (nt + 2 * j) * 16 + l15;
#pragma unroll
            for (int r = 0; r < 4; ++r) {
                int row = mt * 16 + quad * 4 + r;
                sP[row * 420 + col] = f2bf(__expf(sc[j][r] - Mr[r]) * Sr[r]);
            }
        }
        if (full) {
            int col = 24 * 16 + l15;
#pragma unroll
            for (int r = 0; r < 4; ++r) {
                int row = mt * 16 + quad * 4 + r;
                sP[row * 420 + col] = f2bf(__expf(sc[12][r] - Mr[r]) * Sr[r]);
            }
        }
        __syncthreads();

        f32x4 oac = {0.f, 0.f, 0.f, 0.f};
#pragma unroll
        for (int k0 = 0; k0 < 416; k0 += 32) {
            short8 ap = *(const short8*)&sP[(mt * 16 + l15) * 420 + k0 + quad * 8];
            short8 bp = *(const short8*)&sSrcT[(nt * 16 + l15) * 418 + k0 + quad * 8];
            oac = __builtin_amdgcn_mfma_f32_16x16x32_bf16(ap, bp, oac, 0, 0, 0);
        }
        {
            int col = nt * 16 + l15;
#pragma unroll
            for (int r = 0; r < 4; ++r) {
                int rowl = mt * 16 + quad * 4 + r;
                int g = sRows[rowl];
                if (g >= 0) cxtb[(size_t)g * 32 + col] = f2bf(oac[r]);
            }
        }
        __syncthreads();
    }
}

// ---------------------------------------------------------------------------
// MLP: MLP1 via bf16 MFMA (BM=64, BN=256, BK=32) with pre-converted bf16 W1,
// conflict-free LDS strides (As/Bs: 36 ushort = 18 dw -> 2-way;
// HS/W2s: 264 ushort = 132 dw = 4 mod 32 -> 2-way), then MLP2 ALSO via MFMA
// (logits = H @ W2^T, M=64, N=16*ceil(DO/16), K=256) instead of the scalar
// VALU loop whose sAB stride-128dw reads were ~16-way bank-conflicted
// (the measured 4.96e7 SQ_LDS_BANK_CONFLICT).
// LDS layout (59136 B):
//   [0, 23040)        As 64x36 (4608) + Bs 256x36 (18432)   [K-loop]
//   [0, 33792)        HS 64x264 bf16                        [after K-loop]
//   [33792, 59136)    W2s 48x264 bf16 -> later lg 64x49 f32
// ---------------------------------------------------------------------------
template<int DIN, int DO>
__global__ __launch_bounds__(256) void mlp_mfma_kernel(
    const float* __restrict__ X,
    const ushort_t* __restrict__ cxtb,
    const ushort_t* __restrict__ W1bf,   // [256, DIN+32] bf16
    const float* __restrict__ B1,
    const ushort_t* __restrict__ W2bf,   // [DO, 256] bf16
    const float* __restrict__ B2,
    const int* __restrict__ labels,
    float* __restrict__ accum,
    int M)
{
    constexpr int DC = DIN + 32;
    constexpr int KITERS = DC / 32;
    constexpr int ASTR = 36;
    constexpr int HSW = 264;
    constexpr int LGW = 49;
    constexpr int NT2 = (DO + 15) / 16;      // 1 (DO=1,4), 3 (DO=40)

    __shared__ __align__(16) char smem[59136];
    ushort_t* As  = (ushort_t*)smem;                  // 64*36*2  = 4608
    ushort_t* Bs  = (ushort_t*)(smem + 4608);         // 256*36*2 = 18432
    ushort_t* HS  = (ushort_t*)smem;                  // 64*264*2 = 33792 (after K-loop)
    ushort_t* W2s = (ushort_t*)(smem + 33792);        // 48*264*2 <= 25344
    float*    lg  = (float*)(smem + 33792);           // 64*49*4 = 12544 (after MFMA2)

    const int tid = threadIdx.x;
    const int row0 = blockIdx.x * 64;
    const int wave = tid >> 6;
    const int lane = tid & 63;
    const int l15 = lane & 15;
    const int l4 = lane >> 4;

    // ---- stage W2 (bf16) once; pad rows [DO, NT2*16) with zeros ----
    for (int f = tid; f < NT2 * 16 * 32; f += 256) {
        int n = f >> 5, kc = (f & 31) * 8;
        ushort8v v = (ushort8v){0,0,0,0,0,0,0,0};
        if (n < DO) v = *(const ushort8v*)&W2bf[n * 256 + kc];
        *(ushort8v*)&W2s[n * HSW + kc] = v;
    }

    f32x4 acc[4][4];
#pragma unroll
    for (int mi = 0; mi < 4; ++mi)
#pragma unroll
        for (int ni = 0; ni < 4; ++ni)
            acc[mi][ni] = (f32x4){0.f, 0.f, 0.f, 0.f};

    for (int it = 0; it < KITERS; ++it) {
        const int k0 = it * 32;
        // A: X rows (f32->bf16) or cxtb (already bf16)
#pragma unroll
        for (int half = 0; half < 2; ++half) {
            int f = tid + half * 256;
            int row = f >> 3, k4 = (f & 7) * 4;
            ushort4v pk;
            if (k0 < DIN) {
                float4 v = *(const float4*)(X + (size_t)(row0 + row) * DIN + k0 + k4);
                pk[0] = f2bf(v.x); pk[1] = f2bf(v.y);
                pk[2] = f2bf(v.z); pk[3] = f2bf(v.w);
            } else {
                pk = *(const ushort4v*)(cxtb + (size_t)(row0 + row) * 32 + k4);
            }
            *(ushort4v*)&As[row * ASTR + k4] = pk;
        }
        // B: W1bf slice [256][32], b128 copies
#pragma unroll
        for (int i = 0; i < 4; ++i) {
            int f = tid + i * 256;
            int n = f >> 2, kc = (f & 3) * 8;
            *(ushort8v*)&Bs[n * ASTR + kc] =
                *(const ushort8v*)&W1bf[(size_t)n * DC + k0 + kc];
        }
        __syncthreads();

        short8 af[4], bfv[4];
#pragma unroll
        for (int mi = 0; mi < 4; ++mi)
            af[mi] = *(const short8*)&As[(mi * 16 + l15) * ASTR + l4 * 8];
#pragma unroll
        for (int ni = 0; ni < 4; ++ni)
            bfv[ni] = *(const short8*)&Bs[(wave * 64 + ni * 16 + l15) * ASTR + l4 * 8];
#pragma unroll
        for (int mi = 0; mi < 4; ++mi)
#pragma unroll
            for (int ni = 0; ni < 4; ++ni)
                acc[mi][ni] = __builtin_amdgcn_mfma_f32_16x16x32_bf16(
                    af[mi], bfv[ni], acc[mi][ni], 0, 0, 0);
        __syncthreads();
    }

    // ---- H = relu(acc + b1) -> HS (overwrites As/Bs region) ----
    float b1v[4];
#pragma unroll
    for (int ni = 0; ni < 4; ++ni) b1v[ni] = B1[wave * 64 + ni * 16 + l15];
#pragma unroll
    for (int mi = 0; mi < 4; ++mi) {
#pragma unroll
        for (int ni = 0; ni < 4; ++ni) {
            int col = wave * 64 + ni * 16 + l15;
#pragma unroll
            for (int r = 0; r < 4; ++r) {
                int rowl = mi * 16 + l4 * 4 + r;
                float h = fmaxf(acc[mi][ni][r] + b1v[ni], 0.0f);
                HS[rowl * HSW + col] = f2bf(h);
            }
        }
    }
    __syncthreads();

    // ---- MLP2 via MFMA: logits = H @ W2^T; wave = M-tile of 16 rows ----
    f32x4 acc2[NT2];
#pragma unroll
    for (int nti = 0; nti < NT2; ++nti) acc2[nti] = (f32x4){0.f, 0.f, 0.f, 0.f};
#pragma unroll
    for (int kk = 0; kk < 256; kk += 32) {
        short8 af2 = *(const short8*)&HS[(wave * 16 + l15) * HSW + kk + l4 * 8];
#pragma unroll
        for (int nti = 0; nti < NT2; ++nti) {
            short8 bf2 = *(const short8*)&W2s[(nti * 16 + l15) * HSW + kk + l4 * 8];
            acc2[nti] = __builtin_amdgcn_mfma_f32_16x16x32_bf16(af2, bf2, acc2[nti], 0, 0, 0);
        }
    }
    __syncthreads();   // done reading W2s; lg will overwrite it

    // ---- logits + B2 -> lg ----
#pragma unroll
    for (int nti = 0; nti < NT2; ++nti) {
        int col = nti * 16 + l15;
        if (col < DO) {
            float b2 = B2[col];
#pragma unroll
            for (int r = 0; r < 4; ++r)
                lg[(wave * 16 + l4 * 4 + r) * LGW + col] = acc2[nti][r] + b2;
        }
    }
    __syncthreads();

    // ---- loss + acc ----
    float loss_l = 0.0f, cnt_l = 0.0f;
    if (tid < 64) {
        int lab = labels[row0 + tid];
        if (DO == 1) {
            float s = lg[tid * LGW];
            loss_l = fmaxf(s, 0.0f) + log1pf(__expf(-fabsf(s))) - (float)lab * s;
            int pred = (s > 0.0f) ? 1 : 0;
            cnt_l = (pred == lab) ? 1.0f : 0.0f;
        } else {
            const float* lr = &lg[tid * LGW];
            float mx = lr[0];
            int am = 0;
#pragma unroll
            for (int o = 1; o < DO; ++o) {
                float v = lr[o];
                if (v > mx) { mx = v; am = o; }
            }
            float se = 0.0f;
#pragma unroll
            for (int o = 0; o < DO; ++o) se += __expf(lr[o] - mx);
            loss_l = mx + logf(se) - lr[lab];
            cnt_l = (am == lab) ? 1.0f : 0.0f;
        }
#pragma unroll
        for (int off = 32; off > 0; off >>= 1) {
            loss_l += __shfl_down(loss_l, off, 64);
            cnt_l  += __shfl_down(cnt_l, off, 64);
        }
        if (tid == 0) {
            atomicAdd(accum, loss_l);
            atomicAdd(accum + 1, cnt_l);
        }
    }
}

// ---------------------------------------------------------------------------
__global__ void finalize_kernel(const float* __restrict__ acc, float* __restrict__ out) {
    if (threadIdx.x == 0) {
        out[0] = (acc[0] + acc[2] + acc[4]) / (float)BATCH;
        out[1] = acc[3] / (float)NA;
        out[2] = acc[1] / (float)NT;
        out[3] = acc[5] / (float)NBD;
    }
}

// ---------------------------------------------------------------------------
extern "C" void kernel_launch(void* const* d_in, const int* in_sizes, int n_in,
                              void* d_out, int out_size, void* d_ws, size_t ws_size,
                              hipStream_t stream) {
    const float* src      = (const float*)d_in[0];
    const float* topoX    = (const float*)d_in[1];
    const float* atomX    = (const float*)d_in[2];
    const float* bondX    = (const float*)d_in[3];
    const int*   topo_idx = (const int*)d_in[4];
    const int*   atom_idx = (const int*)d_in[5];
    const int*   bond_idx = (const int*)d_in[6];
    const int*   topo_lab = (const int*)d_in[7];
    const int*   atom_lab = (const int*)d_in[8];
    const int*   bond_lab = (const int*)d_in[9];
    const float* Atw = (const float*)d_in[10]; const float* Atb = (const float*)d_in[11];
    const float* Aaw = (const float*)d_in[12]; const float* Aab = (const float*)d_in[13];
    const float* Abw = (const float*)d_in[14]; const float* Abb = (const float*)d_in[15];
    const float* tW1 = (const float*)d_in[16]; const float* tB1 = (const float*)d_in[17];
    const float* tW2 = (const float*)d_in[18]; const float* tB2 = (const float*)d_in[19];
    const float* aW1 = (const float*)d_in[20]; const float* aB1 = (const float*)d_in[21];
    const float* aW2 = (const float*)d_in[22]; const float* aB2 = (const float*)d_in[23];
    const float* bW1 = (const float*)d_in[24]; const float* bB1 = (const float*)d_in[25];
    const float* bW2 = (const float*)d_in[26]; const float* bB2 = (const float*)d_in[27];
    float* out = (float*)d_out;

    char* ws = (char*)d_ws;
    float* acc    = (float*)ws;                       // 8 f
    int*   cnt    = (int*)(ws + 256);                 // 3*256
    int*   cur    = (int*)(ws + 3328);                // 3*256
    int*   bstart = (int*)(ws + 6400);                // 3*256
    int*   bkt_t  = (int*)(ws + 9472);                // NT
    int*   bkt_a  = bkt_t + NT;
    int*   bkt_b  = bkt_a + NA;
    ushort_t* cxtb = (ushort_t*)(ws + 623872);        // NBD*32 bf16
    ushort_t* Qbf  = (ushort_t*)(ws + 5539072);       // NBD*32 bf16  (ends 10454272)
    ushort_t* w1t  = (ushort_t*)(ws + 10454272);      // 256*544 bf16 = 278528 B
    ushort_t* w1a  = (ushort_t*)(ws + 10732800);      // 256*544 bf16 = 278528 B
    ushort_t* w1b  = (ushort_t*)(ws + 11011328);      // 256*800 bf16 = 409600 B
    ushort_t* w2t  = (ushort_t*)(ws + 11420928);      //   1*256 bf16
    ushort_t* w2a  = (ushort_t*)(ws + 11421440);      //  40*256 bf16
    ushort_t* w2b  = (ushort_t*)(ws + 11441920);      //   4*256 bf16

    hipLaunchKernelGGL(init_kernel, dim3(1), dim3(256), 0, stream, acc, cnt);

    // weight pre-conversion (f32 -> bf16), once per launch
    hipLaunchKernelGGL(convbf_kernel, dim3((256*544/4 + 255)/256), dim3(256), 0, stream, tW1, w1t, 256*544/4);
    hipLaunchKernelGGL(convbf_kernel, dim3((256*544/4 + 255)/256), dim3(256), 0, stream, aW1, w1a, 256*544/4);
    hipLaunchKernelGGL(convbf_kernel, dim3((256*800/4 + 255)/256), dim3(256), 0, stream, bW1, w1b, 256*800/4);
    hipLaunchKernelGGL(convbf_kernel, dim3(1), dim3(256), 0, stream, tW2, w2t, 256/4);
    hipLaunchKernelGGL(convbf_kernel, dim3((40*256/4 + 255)/256), dim3(256), 0, stream, aW2, w2a, 40*256/4);
    hipLaunchKernelGGL(convbf_kernel, dim3(1), dim3(256), 0, stream, bW2, w2b, 4*256/4);

    hipLaunchKernelGGL(hist_kernel, dim3(128), dim3(256), 0, stream, topo_idx, NT, cnt + 0);
    hipLaunchKernelGGL(hist_kernel, dim3(128), dim3(256), 0, stream, atom_idx, NA, cnt + 256);
    hipLaunchKernelGGL(hist_kernel, dim3(128), dim3(256), 0, stream, bond_idx, NBD, cnt + 512);
    hipLaunchKernelGGL(scan_kernel, dim3(1), dim3(256), 0, stream, cnt, cur, bstart);
    hipLaunchKernelGGL(scatter_kernel, dim3(256), dim3(256), 0, stream, topo_idx, NT, cur + 0, bkt_t);
    hipLaunchKernelGGL(scatter_kernel, dim3(256), dim3(256), 0, stream, atom_idx, NA, cur + 256, bkt_a);
    hipLaunchKernelGGL(scatter_kernel, dim3(256), dim3(256), 0, stream, bond_idx, NBD, cur + 512, bkt_b);

    // ---- topo head ----
    hipLaunchKernelGGL((qproj_kernel<512>), dim3(NT / 64), dim3(256), 0, stream,
                       topoX, Atw, Atb, Qbf);
    hipLaunchKernelGGL((attn2_kernel<4, 3>), dim3(256 * 3), dim3(256), 0, stream,
                       src, Qbf, bkt_t, bstart + 0, cnt + 0, cxtb);
    hipLaunchKernelGGL((mlp_mfma_kernel<512, 1>), dim3(NT / 64), dim3(256), 0, stream,
                       topoX, cxtb, w1t, tB1, w2t, tB2, topo_lab, acc + 0, NT);

    // ---- atom head ----
    hipLaunchKernelGGL((qproj_kernel<512>), dim3(NA / 64), dim3(256), 0, stream,
                       atomX, Aaw, Aab, Qbf);
    hipLaunchKernelGGL((attn2_kernel<4, 3>), dim3(256 * 3), dim3(256), 0, stream,
                       src, Qbf, bkt_a, bstart + 256, cnt + 256, cxtb);
    hipLaunchKernelGGL((mlp_mfma_kernel<512, 40>), dim3(NA / 64), dim3(256), 0, stream,
                       atomX, cxtb, w1a, aB1, w2a, aB2, atom_lab, acc + 2, NA);

    // ---- bond head ----
    hipLaunchKernelGGL((qproj_kernel<768>), dim3(NBD / 64), dim3(256), 0, stream,
                       bondX, Abw, Abb, Qbf);
    hipLaunchKernelGGL((attn2_kernel<5, 4>), dim3(256 * 4), dim3(256), 0, stream,
                       src, Qbf, bkt_b, bstart + 512, cnt + 512, cxtb);
    hipLaunchKernelGGL((mlp_mfma_kernel<768, 4>), dim3(NBD / 64), dim3(256), 0, stream,
                       bondX, cxtb, w1b, bB1, w2b, bB2, bond_lab, acc + 4, NBD);

    hipLaunchKernelGGL(finalize_kernel, dim3(1), dim3(64), 0, stream, acc, out);
}

// Round 4
// 1170.051 us; speedup vs baseline: 1.0465x; 1.0465x over previous
//
#include <hip/hip_runtime.h>
#include <math.h>

#define LATD 32
#define AV 40
#define NBOND 4
#define BATCH 256
#define LSRC 400
#define NT 38400
#define NA 38400
#define NBD 76800

typedef unsigned short ushort_t;
typedef short short8 __attribute__((ext_vector_type(8)));
typedef float f32x4 __attribute__((ext_vector_type(4)));
typedef unsigned short ushort4v __attribute__((ext_vector_type(4)));
typedef unsigned short ushort8v __attribute__((ext_vector_type(8)));

__device__ __forceinline__ ushort_t f2bf(float f) {
    union { float f; unsigned u; } v; v.f = f;
    unsigned r = v.u + 0x7fffu + ((v.u >> 16) & 1u);   // RTNE
    return (ushort_t)(r >> 16);
}
__device__ __forceinline__ float bf2f(ushort_t u) {
    union { unsigned u; float f; } v; v.u = ((unsigned)u) << 16;
    return v.f;
}

// ---------------------------------------------------------------------------
// init: zero loss accumulators (8 floats) + histogram counts (3*256 ints)
// ---------------------------------------------------------------------------
__global__ void init_kernel(float* acc, int* cnt) {
    int t = threadIdx.x;
    if (t < 8) acc[t] = 0.0f;
    cnt[t] = 0; cnt[t + 256] = 0; cnt[t + 512] = 0;
}

// ---------------------------------------------------------------------------
// convbf: f32 -> bf16 bulk conversion (weights, done once per launch set)
// ---------------------------------------------------------------------------
__global__ __launch_bounds__(256) void convbf_kernel(const float* __restrict__ in,
                                                     ushort_t* __restrict__ out, int n4) {
    int i = blockIdx.x * 256 + threadIdx.x;
    if (i < n4) {
        float4 v = ((const float4*)in)[i];
        ushort4v p;
        p[0] = f2bf(v.x); p[1] = f2bf(v.y); p[2] = f2bf(v.z); p[3] = f2bf(v.w);
        ((ushort4v*)out)[i] = p;
    }
}

// ---------------------------------------------------------------------------
// histogram
// ---------------------------------------------------------------------------
__global__ __launch_bounds__(256) void hist_kernel(const int* __restrict__ idx, int N,
                                                   int* __restrict__ cnt) {
    __shared__ int lc[256];
    int t = threadIdx.x;
    lc[t] = 0;
    __syncthreads();
    for (int i = blockIdx.x * 256 + t; i < N; i += gridDim.x * 256)
        atomicAdd(&lc[idx[i]], 1);
    __syncthreads();
    if (lc[t]) atomicAdd(&cnt[t], lc[t]);
}

// ---------------------------------------------------------------------------
// scan: exclusive prefix over 256 bins, 3 heads
// ---------------------------------------------------------------------------
__global__ __launch_bounds__(256) void scan_kernel(const int* __restrict__ cnt,
                                                   int* __restrict__ cur,
                                                   int* __restrict__ bstart) {
    __shared__ int s[256];
    int t = threadIdx.x;
    for (int h = 0; h < 3; ++h) {
        int v = cnt[h * 256 + t];
        s[t] = v;
        __syncthreads();
        for (int d = 1; d < 256; d <<= 1) {
            int u = (t >= d) ? s[t - d] : 0;
            __syncthreads();
            s[t] += u;
            __syncthreads();
        }
        cur[h * 256 + t] = s[t] - v;
        bstart[h * 256 + t] = s[t] - v;
        __syncthreads();
    }
}

// ---------------------------------------------------------------------------
// scatter: bucket[pos] = row
// ---------------------------------------------------------------------------
__global__ __launch_bounds__(256) void scatter_kernel(const int* __restrict__ idx, int N,
                                                      int* __restrict__ cur,
                                                      int* __restrict__ bucket) {
    for (int i = blockIdx.x * 256 + threadIdx.x; i < N; i += gridDim.x * 256) {
        int b = idx[i];
        int p = atomicAdd(&cur[b], 1);
        bucket[p] = i;
    }
}

// ---------------------------------------------------------------------------
// qproj: Qbf[N,32] = bf16( X[N,DIN] @ Aw^T[DIN,32] + Ab )
// ---------------------------------------------------------------------------
template<int DIN>
__global__ __launch_bounds__(256) void qproj_kernel(
    const float* __restrict__ X,   // [N, DIN]
    const float* __restrict__ Aw,  // [32, DIN]
    const float* __restrict__ Ab,  // [32]
    ushort_t* __restrict__ Qbf)    // [N, 32] bf16
{
    __shared__ ushort_t As[64 * 72];
    __shared__ ushort_t Bs[32 * 72];
    const int tid = threadIdx.x;
    const int wave = tid >> 6, lane = tid & 63;
    const int l15 = lane & 15, quad = lane >> 4;
    const int row0 = blockIdx.x * 64;

    const int ar = tid >> 2;            // 0..63
    const int ak = (tid & 3) * 8;       // 0,8,16,24
    const int br = tid >> 3;            // 0..31
    const int bk = (tid & 7) * 8;       // 0..56

    f32x4 acc0 = {0.f,0.f,0.f,0.f}, acc1 = {0.f,0.f,0.f,0.f};

    for (int k0 = 0; k0 < DIN; k0 += 64) {
        {
            const float* xb = X + (size_t)(row0 + ar) * DIN + k0 + ak;
            float4 v0 = *(const float4*)xb,        v1 = *(const float4*)(xb + 4);
            float4 v2 = *(const float4*)(xb + 32), v3 = *(const float4*)(xb + 36);
            ushort8v p;
            p[0]=f2bf(v0.x); p[1]=f2bf(v0.y); p[2]=f2bf(v0.z); p[3]=f2bf(v0.w);
            p[4]=f2bf(v1.x); p[5]=f2bf(v1.y); p[6]=f2bf(v1.z); p[7]=f2bf(v1.w);
            *(ushort8v*)&As[ar * 72 + ak] = p;
            p[0]=f2bf(v2.x); p[1]=f2bf(v2.y); p[2]=f2bf(v2.z); p[3]=f2bf(v2.w);
            p[4]=f2bf(v3.x); p[5]=f2bf(v3.y); p[6]=f2bf(v3.z); p[7]=f2bf(v3.w);
            *(ushort8v*)&As[ar * 72 + ak + 32] = p;
        }
        {
            const float* wb = Aw + (size_t)br * DIN + k0 + bk;
            float4 w0 = *(const float4*)wb, w1 = *(const float4*)(wb + 4);
            ushort8v p;
            p[0]=f2bf(w0.x); p[1]=f2bf(w0.y); p[2]=f2bf(w0.z); p[3]=f2bf(w0.w);
            p[4]=f2bf(w1.x); p[5]=f2bf(w1.y); p[6]=f2bf(w1.z); p[7]=f2bf(w1.w);
            *(ushort8v*)&Bs[br * 72 + bk] = p;
        }
        __syncthreads();
        short8 a0 = *(const short8*)&As[(wave*16 + l15) * 72 + quad*8];
        short8 a1 = *(const short8*)&As[(wave*16 + l15) * 72 + 32 + quad*8];
        short8 b0 = *(const short8*)&Bs[l15 * 72 + quad*8];
        short8 b1 = *(const short8*)&Bs[l15 * 72 + 32 + quad*8];
        short8 b2 = *(const short8*)&Bs[(16 + l15) * 72 + quad*8];
        short8 b3 = *(const short8*)&Bs[(16 + l15) * 72 + 32 + quad*8];
        acc0 = __builtin_amdgcn_mfma_f32_16x16x32_bf16(a0, b0, acc0, 0, 0, 0);
        acc0 = __builtin_amdgcn_mfma_f32_16x16x32_bf16(a1, b1, acc0, 0, 0, 0);
        acc1 = __builtin_amdgcn_mfma_f32_16x16x32_bf16(a0, b2, acc1, 0, 0, 0);
        acc1 = __builtin_amdgcn_mfma_f32_16x16x32_bf16(a1, b3, acc1, 0, 0, 0);
        __syncthreads();
    }
    const float ab0 = Ab[l15];
    const float ab1 = Ab[16 + l15];
#pragma unroll
    for (int r = 0; r < 4; ++r) {
        int row = row0 + wave*16 + quad*4 + r;
        Qbf[(size_t)row * 32 + l15]      = f2bf(acc0[r] + ab0);
        Qbf[(size_t)row * 32 + 16 + l15] = f2bf(acc1[r] + ab1);
    }
}

// ---------------------------------------------------------------------------
// attn2 (unchanged)
// ---------------------------------------------------------------------------
template<int TPB, int NBLK>
__global__ __launch_bounds__(256) void attn2_kernel(
    const float* __restrict__ src,      // [256, 400, 32]
    const ushort_t* __restrict__ Qbf,   // [N, 32] bf16
    const int* __restrict__ bucket,
    const int* __restrict__ bstart,     // [256]
    const int* __restrict__ cnt,        // [256]
    ushort_t* __restrict__ cxtb)        // [N, 32] bf16
{
    const int m  = blockIdx.x / NBLK;
    const int t0 = (blockIdx.x % NBLK) * TPB;
    const int cm = cnt[m];
    if (t0 * 32 >= cm) return;

    __shared__ __align__(16) char smem[54272];
    ushort_t* sSrcT  = (ushort_t*)(smem);            // [32][418]  26752 B
    ushort_t* sP     = (ushort_t*)(smem + 26752);    // [32][420]  26880 B
    float*    sStats = (float*)(smem + 53632);       // [4][16][2]   512 B
    int*      sRows  = (int*)(smem + 54144);         // [32]         128 B

    const int tid = threadIdx.x;
    const int wave = tid >> 6, lane = tid & 63;
    const int l15 = lane & 15, quad = lane >> 4;
    const int mt = wave & 1;        // q-row half
    const int nt = wave >> 1;       // chunk parity / output d half
    const bool full = (nt == 0);    // 13th chunk active only for parity 0

    {
        const float4* s4 = (const float4*)(src + (size_t)m * (LSRC * LATD));
        for (int i = tid; i < 3200; i += 256) {
            float4 v = s4[i];
            int l = i >> 3, d4 = (i & 7) * 4;
            sSrcT[(d4 + 0) * 418 + l] = f2bf(v.x);
            sSrcT[(d4 + 1) * 418 + l] = f2bf(v.y);
            sSrcT[(d4 + 2) * 418 + l] = f2bf(v.z);
            sSrcT[(d4 + 3) * 418 + l] = f2bf(v.w);
        }
        for (int i = tid; i < 512; i += 256) {
            int d = i >> 4, l = 400 + (i & 15);
            sSrcT[d * 418 + l] = 0;
        }
        for (int i = tid; i < 512; i += 256) {
            int row = i >> 4, col = 400 + (i & 15);
            sP[row * 420 + col] = 0;
        }
    }
    __syncthreads();

    const int Tm = (cm + 31) >> 5;
    const int rem = Tm - t0;
    const int ntiles = rem < TPB ? rem : TPB;

    for (int tt = 0; tt < ntiles; ++tt) {
        const int t = t0 + tt;
        if (tid < 32) {
            int p = t * 32 + tid;
            sRows[tid] = (p < cm) ? bucket[bstart[m] + p] : -1;
        }
        __syncthreads();

        const int grow = sRows[mt * 16 + l15];
        short8 aq = {0,0,0,0,0,0,0,0};
        if (grow >= 0)
            aq = *(const short8*)(Qbf + (size_t)grow * 32 + quad * 8);

        f32x4 sc[13];
#pragma unroll
        for (int j = 0; j < 13; ++j) {
            int c = nt + 2 * j;                 // c<=25; chunk 25 reads zero pad
            int bbase = quad * 8 * 418 + c * 16 + l15;
            short8 bv;
#pragma unroll
            for (int e = 0; e < 8; ++e) bv[e] = (short)sSrcT[bbase + e * 418];
            f32x4 z = {0.f, 0.f, 0.f, 0.f};
            sc[j] = __builtin_amdgcn_mfma_f32_16x16x32_bf16(aq, bv, z, 0, 0, 0);
        }

        float Mr[4], Sr[4];
#pragma unroll
        for (int r = 0; r < 4; ++r) {
            float mx = sc[0][r];
#pragma unroll
            for (int j = 1; j < 12; ++j) mx = fmaxf(mx, sc[j][r]);
            if (full) mx = fmaxf(mx, sc[12][r]);
            float s = 0.f;
#pragma unroll
            for (int j = 0; j < 12; ++j) s += __expf(sc[j][r] - mx);
            if (full) s += __expf(sc[12][r] - mx);
            Mr[r] = mx; Sr[r] = s;
        }
#pragma unroll
        for (int msk = 1; msk < 16; msk <<= 1) {
#pragma unroll
            for (int r = 0; r < 4; ++r) {
                float mo = __shfl_xor(Mr[r], msk, 64);
                float so = __shfl_xor(Sr[r], msk, 64);
                float mn = fmaxf(Mr[r], mo);
                Sr[r] = Sr[r] * __expf(Mr[r] - mn) + so * __expf(mo - mn);
                Mr[r] = mn;
            }
        }
        if (l15 == 0) {
#pragma unroll
            for (int r = 0; r < 4; ++r) {
                sStats[(wave * 16 + quad * 4 + r) * 2 + 0] = Mr[r];
                sStats[(wave * 16 + quad * 4 + r) * 2 + 1] = Sr[r];
            }
        }
        __syncthreads();
        {
            const int pw = wave ^ 2;   // partner wave, same mt, other parity
#pragma unroll
            for (int r = 0; r < 4; ++r) {
                float mo = sStats[(pw * 16 + quad * 4 + r) * 2 + 0];
                float so = sStats[(pw * 16 + quad * 4 + r) * 2 + 1];
                float mn = fmaxf(Mr[r], mo);
                float L = Sr[r] * __expf(Mr[r] - mn) + so * __expf(mo - mn);
                Mr[r] = mn; Sr[r] = 1.0f / L;
            }
        }
#pragma unroll
        for (int j = 0; j < 12; ++j) {
            int col = (nt + 2 * j) * 16 + l15;
#pragma unroll
            for (int r = 0; r < 4; ++r) {
                int row = mt * 16 + quad * 4 + r;
                sP[row * 420 + col] = f2bf(__expf(sc[j][r] - Mr[r]) * Sr[r]);
            }
        }
        if (full) {
            int col = 24 * 16 + l15;
#pragma unroll
            for (int r = 0; r < 4; ++r) {
                int row = mt * 16 + quad * 4 + r;
                sP[row * 420 + col] = f2bf(__expf(sc[12][r] - Mr[r]) * Sr[r]);
            }
        }
        __syncthreads();

        f32x4 oac = {0.f, 0.f, 0.f, 0.f};
#pragma unroll
        for (int k0 = 0; k0 < 416; k0 += 32) {
            short8 ap = *(const short8*)&sP[(mt * 16 + l15) * 420 + k0 + quad * 8];
            short8 bp = *(const short8*)&sSrcT[(nt * 16 + l15) * 418 + k0 + quad * 8];
            oac = __builtin_amdgcn_mfma_f32_16x16x32_bf16(ap, bp, oac, 0, 0, 0);
        }
        {
            int col = nt * 16 + l15;
#pragma unroll
            for (int r = 0; r < 4; ++r) {
                int rowl = mt * 16 + quad * 4 + r;
                int g = sRows[rowl];
                if (g >= 0) cxtb[(size_t)g * 32 + col] = f2bf(oac[r]);
            }
        }
        __syncthreads();
    }
}

// ---------------------------------------------------------------------------
// MLP: MLP1 bf16 MFMA (BM=64, BN=256, BK=32) + MFMA MLP2 + loss.
// Round-4 changes (occupancy + latency pipeline):
//  - W2 fragments loaded straight from global in the MLP2 loop (L2-hot,
//    identical across blocks) -> W2s LDS staging removed.
//  - lg overlays the smem base (HS reads barrier-complete before write).
//  - LDS 59392 -> 33792 B  => 4 blocks/CU (was 2).
//  - K-loop software-pipelined: iter it+1's global loads (X 2xfloat4,
//    W1bf 4xb128 into regs) issue right after the write-barrier and fly
//    during iter it's fragment reads + 16 MFMAs (T14 async-split).
// LDS layout: K-loop As[64x36]+Bs[256x36]=23040 | HS 64x264x2=33792 | lg 12544
// ---------------------------------------------------------------------------
template<int DIN, int DO>
__global__ __launch_bounds__(256) void mlp_mfma_kernel(
    const float* __restrict__ X,
    const ushort_t* __restrict__ cxtb,
    const ushort_t* __restrict__ W1bf,   // [256, DIN+32] bf16
    const float* __restrict__ B1,
    const ushort_t* __restrict__ W2bf,   // [DO, 256] bf16
    const float* __restrict__ B2,
    const int* __restrict__ labels,
    float* __restrict__ accum,
    int M)
{
    constexpr int DC = DIN + 32;
    constexpr int KX = DIN / 32;         // X-sourced K-iterations
    constexpr int ASTR = 36;
    constexpr int HSW = 264;
    constexpr int LGW = 49;
    constexpr int NT2 = (DO + 15) / 16;  // 1 (DO=1,4), 3 (DO=40)

    __shared__ __align__(16) char smem[33792];
    ushort_t* As = (ushort_t*)smem;                  // 64*36*2  = 4608
    ushort_t* Bs = (ushort_t*)(smem + 4608);         // 256*36*2 = 18432
    ushort_t* HS = (ushort_t*)smem;                  // 64*264*2 = 33792 (post K-loop)
    float*    lg = (float*)smem;                     // 64*49*4  = 12544 (post MLP2)

    const int tid = threadIdx.x;
    const int row0 = blockIdx.x * 64;
    const int wave = tid >> 6;
    const int lane = tid & 63;
    const int l15 = lane & 15;
    const int l4 = lane >> 4;

    // staging maps
    const int arow = tid >> 3;             // 0..31 (and +32 for second half)
    const int akc  = (tid & 7) * 4;        // 0..28
    const int bn   = tid >> 2;             // 0..63 (+64*i)
    const int bkc  = (tid & 3) * 8;        // 0,8,16,24

    f32x4 acc[4][4];
#pragma unroll
    for (int mi = 0; mi < 4; ++mi)
#pragma unroll
        for (int ni = 0; ni < 4; ++ni)
            acc[mi][ni] = (f32x4){0.f, 0.f, 0.f, 0.f};

    // ---- pipeline registers ----
    float4 va0, va1;
    ushort4v pcx0, pcx1;
    ushort8v pb0, pb1, pb2, pb3;

    // prologue: loads for it=0
    va0 = *(const float4*)(X + (size_t)(row0 + arow) * DIN + akc);
    va1 = *(const float4*)(X + (size_t)(row0 + arow + 32) * DIN + akc);
    pb0 = *(const ushort8v*)&W1bf[(size_t)(bn)       * DC + bkc];
    pb1 = *(const ushort8v*)&W1bf[(size_t)(bn + 64)  * DC + bkc];
    pb2 = *(const ushort8v*)&W1bf[(size_t)(bn + 128) * DC + bkc];
    pb3 = *(const ushort8v*)&W1bf[(size_t)(bn + 192) * DC + bkc];

    for (int it = 0; it < KX; ++it) {
        // ---- write staged regs to LDS ----
        {
            ushort4v p0, p1;
            p0[0]=f2bf(va0.x); p0[1]=f2bf(va0.y); p0[2]=f2bf(va0.z); p0[3]=f2bf(va0.w);
            p1[0]=f2bf(va1.x); p1[1]=f2bf(va1.y); p1[2]=f2bf(va1.z); p1[3]=f2bf(va1.w);
            *(ushort4v*)&As[arow * ASTR + akc] = p0;
            *(ushort4v*)&As[(arow + 32) * ASTR + akc] = p1;
            *(ushort8v*)&Bs[(bn)       * ASTR + bkc] = pb0;
            *(ushort8v*)&Bs[(bn + 64)  * ASTR + bkc] = pb1;
            *(ushort8v*)&Bs[(bn + 128) * ASTR + bkc] = pb2;
            *(ushort8v*)&Bs[(bn + 192) * ASTR + bkc] = pb3;
        }
        __syncthreads();

        // ---- issue next iteration's global loads (fly under the MFMAs) ----
        if (it + 1 < KX) {
            const int k1 = (it + 1) * 32;
            va0 = *(const float4*)(X + (size_t)(row0 + arow) * DIN + k1 + akc);
            va1 = *(const float4*)(X + (size_t)(row0 + arow + 32) * DIN + k1 + akc);
            pb0 = *(const ushort8v*)&W1bf[(size_t)(bn)       * DC + k1 + bkc];
            pb1 = *(const ushort8v*)&W1bf[(size_t)(bn + 64)  * DC + k1 + bkc];
            pb2 = *(const ushort8v*)&W1bf[(size_t)(bn + 128) * DC + k1 + bkc];
            pb3 = *(const ushort8v*)&W1bf[(size_t)(bn + 192) * DC + k1 + bkc];
        } else {
            const int k1 = DIN;
            pcx0 = *(const ushort4v*)(cxtb + (size_t)(row0 + arow) * 32 + akc);
            pcx1 = *(const ushort4v*)(cxtb + (size_t)(row0 + arow + 32) * 32 + akc);
            pb0 = *(const ushort8v*)&W1bf[(size_t)(bn)       * DC + k1 + bkc];
            pb1 = *(const ushort8v*)&W1bf[(size_t)(bn + 64)  * DC + k1 + bkc];
            pb2 = *(const ushort8v*)&W1bf[(size_t)(bn + 128) * DC + k1 + bkc];
            pb3 = *(const ushort8v*)&W1bf[(size_t)(bn + 192) * DC + k1 + bkc];
        }

        // ---- fragments + MFMA ----
        {
            short8 af[4], bfv[4];
#pragma unroll
            for (int mi = 0; mi < 4; ++mi)
                af[mi] = *(const short8*)&As[(mi * 16 + l15) * ASTR + l4 * 8];
#pragma unroll
            for (int ni = 0; ni < 4; ++ni)
                bfv[ni] = *(const short8*)&Bs[(wave * 64 + ni * 16 + l15) * ASTR + l4 * 8];
#pragma unroll
            for (int mi = 0; mi < 4; ++mi)
#pragma unroll
                for (int ni = 0; ni < 4; ++ni)
                    acc[mi][ni] = __builtin_amdgcn_mfma_f32_16x16x32_bf16(
                        af[mi], bfv[ni], acc[mi][ni], 0, 0, 0);
        }
        __syncthreads();
    }

    // ---- final K-iteration: cxtb columns ----
    {
        *(ushort4v*)&As[arow * ASTR + akc] = pcx0;
        *(ushort4v*)&As[(arow + 32) * ASTR + akc] = pcx1;
        *(ushort8v*)&Bs[(bn)       * ASTR + bkc] = pb0;
        *(ushort8v*)&Bs[(bn + 64)  * ASTR + bkc] = pb1;
        *(ushort8v*)&Bs[(bn + 128) * ASTR + bkc] = pb2;
        *(ushort8v*)&Bs[(bn + 192) * ASTR + bkc] = pb3;
    }
    __syncthreads();
    {
        short8 af[4], bfv[4];
#pragma unroll
        for (int mi = 0; mi < 4; ++mi)
            af[mi] = *(const short8*)&As[(mi * 16 + l15) * ASTR + l4 * 8];
#pragma unroll
        for (int ni = 0; ni < 4; ++ni)
            bfv[ni] = *(const short8*)&Bs[(wave * 64 + ni * 16 + l15) * ASTR + l4 * 8];
#pragma unroll
        for (int mi = 0; mi < 4; ++mi)
#pragma unroll
            for (int ni = 0; ni < 4; ++ni)
                acc[mi][ni] = __builtin_amdgcn_mfma_f32_16x16x32_bf16(
                    af[mi], bfv[ni], acc[mi][ni], 0, 0, 0);
    }
    __syncthreads();   // all frag reads done before HS overwrites As/Bs

    // ---- H = relu(acc + b1) -> HS ----
    float b1v[4];
#pragma unroll
    for (int ni = 0; ni < 4; ++ni) b1v[ni] = B1[wave * 64 + ni * 16 + l15];
#pragma unroll
    for (int mi = 0; mi < 4; ++mi) {
#pragma unroll
        for (int ni = 0; ni < 4; ++ni) {
            int col = wave * 64 + ni * 16 + l15;
#pragma unroll
            for (int r = 0; r < 4; ++r) {
                int rowl = mi * 16 + l4 * 4 + r;
                float h = fmaxf(acc[mi][ni][r] + b1v[ni], 0.0f);
                HS[rowl * HSW + col] = f2bf(h);
            }
        }
    }
    __syncthreads();

    // ---- MLP2 via MFMA: logits = H @ W2^T; W2 frags straight from global ----
    f32x4 acc2[NT2];
#pragma unroll
    for (int nti = 0; nti < NT2; ++nti) acc2[nti] = (f32x4){0.f, 0.f, 0.f, 0.f};
#pragma unroll
    for (int kk = 0; kk < 256; kk += 32) {
        short8 af2 = *(const short8*)&HS[(wave * 16 + l15) * HSW + kk + l4 * 8];
#pragma unroll
        for (int nti = 0; nti < NT2; ++nti) {
            short8 bw = {0,0,0,0,0,0,0,0};
            int n = nti * 16 + l15;
            if (n < DO)
                bw = *(const short8*)&W2bf[n * 256 + kk + l4 * 8];
            acc2[nti] = __builtin_amdgcn_mfma_f32_16x16x32_bf16(af2, bw, acc2[nti], 0, 0, 0);
        }
    }
    __syncthreads();   // HS reads done; lg overlays smem base

    // ---- logits + B2 -> lg ----
#pragma unroll
    for (int nti = 0; nti < NT2; ++nti) {
        int col = nti * 16 + l15;
        if (col < DO) {
            float b2 = B2[col];
#pragma unroll
            for (int r = 0; r < 4; ++r)
                lg[(wave * 16 + l4 * 4 + r) * LGW + col] = acc2[nti][r] + b2;
        }
    }
    __syncthreads();

    // ---- loss + acc ----
    float loss_l = 0.0f, cnt_l = 0.0f;
    if (tid < 64) {
        int lab = labels[row0 + tid];
        if (DO == 1) {
            float s = lg[tid * LGW];
            loss_l = fmaxf(s, 0.0f) + log1pf(__expf(-fabsf(s))) - (float)lab * s;
            int pred = (s > 0.0f) ? 1 : 0;
            cnt_l = (pred == lab) ? 1.0f : 0.0f;
        } else {
            const float* lr = &lg[tid * LGW];
            float mx = lr[0];
            int am = 0;
#pragma unroll
            for (int o = 1; o < DO; ++o) {
                float v = lr[o];
                if (v > mx) { mx = v; am = o; }
            }
            float se = 0.0f;
#pragma unroll
            for (int o = 0; o < DO; ++o) se += __expf(lr[o] - mx);
            loss_l = mx + logf(se) - lr[lab];
            cnt_l = (am == lab) ? 1.0f : 0.0f;
        }
#pragma unroll
        for (int off = 32; off > 0; off >>= 1) {
            loss_l += __shfl_down(loss_l, off, 64);
            cnt_l  += __shfl_down(cnt_l, off, 64);
        }
        if (tid == 0) {
            atomicAdd(accum, loss_l);
            atomicAdd(accum + 1, cnt_l);
        }
    }
}

// ---------------------------------------------------------------------------
__global__ void finalize_kernel(const float* __restrict__ acc, float* __restrict__ out) {
    if (threadIdx.x == 0) {
        out[0] = (acc[0] + acc[2] + acc[4]) / (float)BATCH;
        out[1] = acc[3] / (float)NA;
        out[2] = acc[1] / (float)NT;
        out[3] = acc[5] / (float)NBD;
    }
}

// ---------------------------------------------------------------------------
extern "C" void kernel_launch(void* const* d_in, const int* in_sizes, int n_in,
                              void* d_out, int out_size, void* d_ws, size_t ws_size,
                              hipStream_t stream) {
    const float* src      = (const float*)d_in[0];
    const float* topoX    = (const float*)d_in[1];
    const float* atomX    = (const float*)d_in[2];
    const float* bondX    = (const float*)d_in[3];
    const int*   topo_idx = (const int*)d_in[4];
    const int*   atom_idx = (const int*)d_in[5];
    const int*   bond_idx = (const int*)d_in[6];
    const int*   topo_lab = (const int*)d_in[7];
    const int*   atom_lab = (const int*)d_in[8];
    const int*   bond_lab = (const int*)d_in[9];
    const float* Atw = (const float*)d_in[10]; const float* Atb = (const float*)d_in[11];
    const float* Aaw = (const float*)d_in[12]; const float* Aab = (const float*)d_in[13];
    const float* Abw = (const float*)d_in[14]; const float* Abb = (const float*)d_in[15];
    const float* tW1 = (const float*)d_in[16]; const float* tB1 = (const float*)d_in[17];
    const float* tW2 = (const float*)d_in[18]; const float* tB2 = (const float*)d_in[19];
    const float* aW1 = (const float*)d_in[20]; const float* aB1 = (const float*)d_in[21];
    const float* aW2 = (const float*)d_in[22]; const float* aB2 = (const float*)d_in[23];
    const float* bW1 = (const float*)d_in[24]; const float* bB1 = (const float*)d_in[25];
    const float* bW2 = (const float*)d_in[26]; const float* bB2 = (const float*)d_in[27];
    float* out = (float*)d_out;

    char* ws = (char*)d_ws;
    float* acc    = (float*)ws;                       // 8 f
    int*   cnt    = (int*)(ws + 256);                 // 3*256
    int*   cur    = (int*)(ws + 3328);                // 3*256
    int*   bstart = (int*)(ws + 6400);                // 3*256
    int*   bkt_t  = (int*)(ws + 9472);                // NT
    int*   bkt_a  = bkt_t + NT;
    int*   bkt_b  = bkt_a + NA;
    ushort_t* cxtb = (ushort_t*)(ws + 623872);        // NBD*32 bf16
    ushort_t* Qbf  = (ushort_t*)(ws + 5539072);       // NBD*32 bf16  (ends 10454272)
    ushort_t* w1t  = (ushort_t*)(ws + 10454272);      // 256*544 bf16 = 278528 B
    ushort_t* w1a  = (ushort_t*)(ws + 10732800);      // 256*544 bf16 = 278528 B
    ushort_t* w1b  = (ushort_t*)(ws + 11011328);      // 256*800 bf16 = 409600 B
    ushort_t* w2t  = (ushort_t*)(ws + 11420928);      //   1*256 bf16
    ushort_t* w2a  = (ushort_t*)(ws + 11421440);      //  40*256 bf16
    ushort_t* w2b  = (ushort_t*)(ws + 11441920);      //   4*256 bf16

    hipLaunchKernelGGL(init_kernel, dim3(1), dim3(256), 0, stream, acc, cnt);

    // weight pre-conversion (f32 -> bf16), once per launch
    hipLaunchKernelGGL(convbf_kernel, dim3((256*544/4 + 255)/256), dim3(256), 0, stream, tW1, w1t, 256*544/4);
    hipLaunchKernelGGL(convbf_kernel, dim3((256*544/4 + 255)/256), dim3(256), 0, stream, aW1, w1a, 256*544/4);
    hipLaunchKernelGGL(convbf_kernel, dim3((256*800/4 + 255)/256), dim3(256), 0, stream, bW1, w1b, 256*800/4);
    hipLaunchKernelGGL(convbf_kernel, dim3(1), dim3(256), 0, stream, tW2, w2t, 256/4);
    hipLaunchKernelGGL(convbf_kernel, dim3((40*256/4 + 255)/256), dim3(256), 0, stream, aW2, w2a, 40*256/4);
    hipLaunchKernelGGL(convbf_kernel, dim3(1), dim3(256), 0, stream, bW2, w2b, 4*256/4);

    hipLaunchKernelGGL(hist_kernel, dim3(128), dim3(256), 0, stream, topo_idx, NT, cnt + 0);
    hipLaunchKernelGGL(hist_kernel, dim3(128), dim3(256), 0, stream, atom_idx, NA, cnt + 256);
    hipLaunchKernelGGL(hist_kernel, dim3(128), dim3(256), 0, stream, bond_idx, NBD, cnt + 512);
    hipLaunchKernelGGL(scan_kernel, dim3(1), dim3(256), 0, stream, cnt, cur, bstart);
    hipLaunchKernelGGL(scatter_kernel, dim3(256), dim3(256), 0, stream, topo_idx, NT, cur + 0, bkt_t);
    hipLaunchKernelGGL(scatter_kernel, dim3(256), dim3(256), 0, stream, atom_idx, NA, cur + 256, bkt_a);
    hipLaunchKernelGGL(scatter_kernel, dim3(256), dim3(256), 0, stream, bond_idx, NBD, cur + 512, bkt_b);

    // ---- topo head ----
    hipLaunchKernelGGL((qproj_kernel<512>), dim3(NT / 64), dim3(256), 0, stream,
                       topoX, Atw, Atb, Qbf);
    hipLaunchKernelGGL((attn2_kernel<4, 3>), dim3(256 * 3), dim3(256), 0, stream,
                       src, Qbf, bkt_t, bstart + 0, cnt + 0, cxtb);
    hipLaunchKernelGGL((mlp_mfma_kernel<512, 1>), dim3(NT / 64), dim3(256), 0, stream,
                       topoX, cxtb, w1t, tB1, w2t, tB2, topo_lab, acc + 0, NT);

    // ---- atom head ----
    hipLaunchKernelGGL((qproj_kernel<512>), dim3(NA / 64), dim3(256), 0, stream,
                       atomX, Aaw, Aab, Qbf);
    hipLaunchKernelGGL((attn2_kernel<4, 3>), dim3(256 * 3), dim3(256), 0, stream,
                       src, Qbf, bkt_a, bstart + 256, cnt + 256, cxtb);
    hipLaunchKernelGGL((mlp_mfma_kernel<512, 40>), dim3(NA / 64), dim3(256), 0, stream,
                       atomX, cxtb, w1a, aB1, w2a, aB2, atom_lab, acc + 2, NA);

    // ---- bond head ----
    hipLaunchKernelGGL((qproj_kernel<768>), dim3(NBD / 64), dim3(256), 0, stream,
                       bondX, Abw, Abb, Qbf);
    hipLaunchKernelGGL((attn2_kernel<5, 4>), dim3(256 * 4), dim3(256), 0, stream,
                       src, Qbf, bkt_b, bstart + 512, cnt + 512, cxtb);
    hipLaunchKernelGGL((mlp_mfma_kernel<768, 4>), dim3(NBD / 64), dim3(256), 0, stream,
                       bondX, cxtb, w1b, bB1, w2b, bB2, bond_lab, acc + 4, NBD);

    hipLaunchKernelGGL(finalize_kernel, dim3(1), dim3(64), 0, stream, acc, out);
}